// Round 5
// baseline (236.878 us; speedup 1.0000x reference)
//
#include <hip/hip_runtime.h>
#include <hip/hip_bf16.h>

// Problem constants: G=64, C=32, L=128, D=64, H=128, NCLS=10
#define NSEQ 2048   // G*C
#define LSEQ 128
#define DIN  64
#define HID  128
#define NCLS 10
#define XPAD 72     // padded x row (f16 elems)
#define CHK  16     // timesteps staged per chunk

typedef _Float16 f16x8 __attribute__((ext_vector_type(8)));  // MFMA A/B frag (4 VGPR)
typedef float    facc4 __attribute__((ext_vector_type(4)));  // MFMA C/D frag
typedef unsigned uint2v __attribute__((ext_vector_type(2)));

__device__ __forceinline__ f16x8 load_f16_frag(const float* __restrict__ p) {
    f16x8 r;
#pragma unroll
    for (int j = 0; j < 8; ++j) r[j] = (_Float16)p[j];
    return r;
}

__device__ __forceinline__ float fast_sigmoid(float x) {
    float e = __builtin_amdgcn_exp2f(-1.4426950408889634f * x);
    return __builtin_amdgcn_rcpf(1.0f + e);
}
__device__ __forceinline__ float fast_tanh(float x) {
    float e = __builtin_amdgcn_exp2f(2.8853900817779268f * x);
    return 1.0f - 2.0f * __builtin_amdgcn_rcpf(1.0f + e);
}

// u[l<32] = a[l] (row r of own quad), u[l>=32] = b[l-32] (row r+2 of opposite half)
__device__ __forceinline__ float half_exchange(float a, float b, bool hi) {
#if __has_builtin(__builtin_amdgcn_permlane32_swap)
    uint2v r = __builtin_amdgcn_permlane32_swap(
        __builtin_bit_cast(unsigned, a), __builtin_bit_cast(unsigned, b), false, false);
    return __builtin_bit_cast(float, r.x);
#else
    float bx = __shfl_xor(b, 32);
    return hi ? bx : a;
#endif
}

// One block = 8 sequences (M=16 padded), 8 waves; wave w owns gate columns
// {g*128 + w*16} -> lane's 4 C-frags are i,f,g,o of its 16 hidden units.
// permlane32_swap redistributes the 8 valid C-rows so all 64 lanes run 2
// valid cell-units (seq map qd0:{0,1} qd1:{4,5} qd2:{2,3} qd3:{6,7}).
// Epilogue fused: blocks atomicAdd scaled h-sums into mean[64][128] (ws),
// ticket-last block computes classifier + log-softmax (no spinning).
__global__ __launch_bounds__(512) void lstm_fused(
    const float* __restrict__ x,      // [2048][128][64] f32
    const float* __restrict__ Wih,    // [512][64] f32
    const float* __restrict__ Whh,    // [512][128] f32
    const float* __restrict__ bih,    // [512] f32
    const float* __restrict__ bhh,    // [512] f32
    const float* __restrict__ Wcls,   // [10][128] f32
    const float* __restrict__ bcls,   // [10] f32
    float* __restrict__ meanf,        // [64][128] f32 (ws, zeroed per launch)
    unsigned* __restrict__ ticket,    // 1 u32 (ws, zeroed per launch)
    float* __restrict__ out)          // [64][10] f32
{
    __shared__ __align__(16) _Float16 hbuf[2][16][136];          // 8704 B
    __shared__ __align__(16) _Float16 xs[2][CHK][8][XPAD];       // 36864 B
    __shared__ float logit_s[64 * NCLS];                         // 2560 B
    __shared__ unsigned tick_s;

    const int tid  = threadIdx.x;
    const int w    = tid >> 6;
    const int lane = tid & 63;
    const int ln   = lane & 15;
    const int qd   = lane >> 4;
    const int s0   = blockIdx.x * 8;
    const int khid = w * 16 + ln;
    const int sq0  = (qd & 1) * 4 + (qd >> 1) * 2;   // {0,4,2,6}
    const int sq1  = sq0 + 1;                        // {1,5,3,7}
    const bool hi  = (qd >= 2);

    // ---- weight B-fragments: f32 -> f16 registers (reused all 128 steps) ----
    f16x8 whh[4][4];
    f16x8 wih[4][2];
    facc4 biasf[4];     // persistent C-input fragment: bias broadcast over rows
#pragma unroll
    for (int g = 0; g < 4; ++g) {
        const int col = g * HID + khid;
        float b = bih[col] + bhh[col];
        biasf[g] = (facc4){b, b, b, b};
#pragma unroll
        for (int k0 = 0; k0 < 4; ++k0)
            whh[g][k0] = load_f16_frag(Whh + col * HID + k0 * 32 + qd * 8);
#pragma unroll
        for (int k0 = 0; k0 < 2; ++k0)
            wih[g][k0] = load_f16_frag(Wih + col * DIN + k0 * 32 + qd * 8);
    }

    // zero both h buffers (rows 8..15 stay zero -> padded M rows read 0)
    {
        unsigned int* p = (unsigned int*)&hbuf[0][0][0];
        for (int i = tid; i < 2 * 16 * 136 / 2; i += 512) p[i] = 0u;
    }

    // x staging: wave w stages sequence s0+w; lane covers 16 consecutive f32.
    const float* xsrc = x + (size_t)(s0 + w) * (LSEQ * DIN) + lane * 16;
    const int stt = lane >> 2;
    const int sdd = (lane & 3) * 16;

    {   // stage chunk 0
        float4 a0 = ((const float4*)xsrc)[0];
        float4 a1 = ((const float4*)xsrc)[1];
        float4 a2 = ((const float4*)xsrc)[2];
        float4 a3 = ((const float4*)xsrc)[3];
        f16x8 o0, o1;
#pragma unroll
        for (int j = 0; j < 4; ++j) { o0[j] = (_Float16)((float*)&a0)[j]; o0[4+j] = (_Float16)((float*)&a1)[j]; }
#pragma unroll
        for (int j = 0; j < 4; ++j) { o1[j] = (_Float16)((float*)&a2)[j]; o1[4+j] = (_Float16)((float*)&a3)[j]; }
        *(f16x8*)&xs[0][stt][w][sdd]     = o0;
        *(f16x8*)&xs[0][stt][w][sdd + 8] = o1;
    }

    float cst[2]  = {0.f, 0.f};
    float hsum[2] = {0.f, 0.f};

    __syncthreads();

    // prologue: acc for t=0 = bias + x(0) @ Wih^T
    facc4 accA[4], accB[4];
    {
        f16x8 x0 = *(const f16x8*)(&xs[0][0][ln & 7][qd * 8]);
        f16x8 x1 = *(const f16x8*)(&xs[0][0][ln & 7][32 + qd * 8]);
#pragma unroll
        for (int g = 0; g < 4; ++g) {
            accA[g] = __builtin_amdgcn_mfma_f32_16x16x32_f16(x0, wih[g][0], biasf[g], 0, 0, 0);
            accA[g] = __builtin_amdgcn_mfma_f32_16x16x32_f16(x1, wih[g][1], accA[g], 0, 0, 0);
        }
    }

    int cur = 0;

#define STEP(ACCIN, ACCOUT, CT)                                                          \
    {                                                                                    \
        const int ct = (CT);                                                             \
        /* h A-frags (post-barrier critical path) */                                     \
        f16x8 hf[4];                                                                     \
        _Pragma("unroll")                                                                \
        for (int k0 = 0; k0 < 4; ++k0)                                                   \
            hf[k0] = *(const f16x8*)(&hbuf[cur][ln][k0 * 32 + qd * 8]);                  \
        /* x A-frags for t+1 */                                                          \
        const int nbuf = (ct < CHK - 1) ? buf : (buf ^ 1);                               \
        const int nct  = (ct + 1) & (CHK - 1);                                           \
        f16x8 xf0 = *(const f16x8*)(&xs[nbuf][nct][ln & 7][qd * 8]);                     \
        f16x8 xf1 = *(const f16x8*)(&xs[nbuf][nct][ln & 7][32 + qd * 8]);                \
        /* h-part MFMAs into carried acc (already holds bias + x(t)) */                  \
        _Pragma("unroll")                                                                \
        for (int g = 0; g < 4; ++g)                                                      \
            _Pragma("unroll")                                                            \
            for (int k0 = 0; k0 < 4; ++k0)                                               \
                ACCIN[g] = __builtin_amdgcn_mfma_f32_16x16x32_f16(hf[k0], whh[g][k0], ACCIN[g], 0, 0, 0); \
        /* redistribute valid rows: lane gets its 2 units (1 VALU op each) */            \
        float u0[4], u1[4];                                                              \
        _Pragma("unroll")                                                                \
        for (int g = 0; g < 4; ++g) {                                                    \
            u0[g] = half_exchange(ACCIN[g][0], ACCIN[g][2], hi);                         \
            u1[g] = half_exchange(ACCIN[g][1], ACCIN[g][3], hi);                         \
        }                                                                                \
        /* next step's x-part: fills MFMA pipe during cell phase */                      \
        _Pragma("unroll")                                                                \
        for (int g = 0; g < 4; ++g) {                                                    \
            ACCOUT[g] = __builtin_amdgcn_mfma_f32_16x16x32_f16(xf0, wih[g][0], biasf[g], 0, 0, 0); \
            ACCOUT[g] = __builtin_amdgcn_mfma_f32_16x16x32_f16(xf1, wih[g][1], ACCOUT[g], 0, 0, 0); \
        }                                                                                \
        if (ct == 0 && more) {      /* issue next chunk's global loads */                \
            const float* p = xsrc + (chunk + 1) * (CHK * DIN);                           \
            l0 = ((const float4*)p)[0];                                                  \
            l1 = ((const float4*)p)[1];                                                  \
            l2 = ((const float4*)p)[2];                                                  \
            l3 = ((const float4*)p)[3];                                                  \
        }                                                                                \
        if (ct == 12 && more) {     /* convert + write next chunk to LDS */              \
            f16x8 o0, o1;                                                                \
            _Pragma("unroll")                                                            \
            for (int j = 0; j < 4; ++j) { o0[j] = (_Float16)((float*)&l0)[j]; o0[4+j] = (_Float16)((float*)&l1)[j]; } \
            _Pragma("unroll")                                                            \
            for (int j = 0; j < 4; ++j) { o1[j] = (_Float16)((float*)&l2)[j]; o1[4+j] = (_Float16)((float*)&l3)[j]; } \
            *(f16x8*)&xs[buf ^ 1][stt][w][sdd]     = o0;                                 \
            *(f16x8*)&xs[buf ^ 1][stt][w][sdd + 8] = o1;                                 \
        }                                                                                \
        /* LSTM cell on this lane's 2 assigned (seq, hid) units */                       \
        _Float16 hb[2];                                                                  \
        _Pragma("unroll")                                                                \
        for (int j = 0; j < 2; ++j) {                                                    \
            float g0v = j ? u1[0] : u0[0];                                               \
            float g1v = j ? u1[1] : u0[1];                                               \
            float g2v = j ? u1[2] : u0[2];                                               \
            float g3v = j ? u1[3] : u0[3];                                               \
            float iv = fast_sigmoid(g0v);                                                \
            float fv = fast_sigmoid(g1v);                                                \
            float gv = fast_tanh(g2v);                                                   \
            float ov = fast_sigmoid(g3v);                                                \
            float c  = fv * cst[j] + iv * gv;                                            \
            cst[j]   = c;                                                                \
            float hv = ov * fast_tanh(c);                                                \
            hsum[j] += hv;                                                               \
            hb[j]    = (_Float16)hv;                                                     \
        }                                                                                \
        hbuf[cur ^ 1][sq0][khid] = hb[0];                                                \
        hbuf[cur ^ 1][sq1][khid] = hb[1];                                                \
        __syncthreads();                                                                 \
        cur ^= 1;                                                                        \
    }

    for (int chunk = 0; chunk < LSEQ / CHK; ++chunk) {
        const int buf = chunk & 1;
        const bool more = chunk < (LSEQ / CHK - 1);
        float4 l0, l1, l2, l3;
#pragma unroll 1
        for (int ct2 = 0; ct2 < CHK / 2; ++ct2) {
            STEP(accA, accB, 2 * ct2);
            STEP(accB, accA, 2 * ct2 + 1);
        }
    }
#undef STEP

    // graph-mean accumulation: both units share (graph, khid) -> one atomicAdd
    atomicAdd(meanf + (s0 >> 5) * HID + khid, (hsum[0] + hsum[1]) * (1.0f / 32.0f));

    // ---- fused epilogue: last block to finish runs the classifier ----
    __threadfence();            // release: make mean adds visible device-wide
    __syncthreads();            // all threads of block done adding
    if (tid == 0) tick_s = atomicAdd(ticket, 1u);
    __syncthreads();
    if (tick_s == 255u) {       // block-uniform condition
        __threadfence();        // acquire
        for (int d = tid; d < 64 * NCLS; d += 512) {
            const int g  = d / NCLS;
            const int cl = d - g * NCLS;
            float acc = bcls[cl];
            const float* mrow = meanf + g * HID;
            const float* wrow = Wcls + cl * HID;
#pragma unroll 8
            for (int k = 0; k < HID; ++k)
                acc += mrow[k] * wrow[k];
            logit_s[d] = acc;
        }
        __syncthreads();
        if (tid < 64) {
            const float* lg = logit_s + tid * NCLS;
            float mx = lg[0];
#pragma unroll
            for (int j = 1; j < NCLS; ++j) mx = fmaxf(mx, lg[j]);
            float se = 0.f;
#pragma unroll
            for (int j = 0; j < NCLS; ++j)
                se += __builtin_amdgcn_exp2f((lg[j] - mx) * 1.4426950408889634f);
            float lse = mx + 0.6931471805599453f * __builtin_amdgcn_logf(se);
#pragma unroll
            for (int j = 0; j < NCLS; ++j)
                out[tid * NCLS + j] = lg[j] - lse;
        }
    }
}

extern "C" void kernel_launch(void* const* d_in, const int* in_sizes, int n_in,
                              void* d_out, int out_size, void* d_ws, size_t ws_size,
                              hipStream_t stream) {
    const float* x    = (const float*)d_in[0];
    const float* Wih  = (const float*)d_in[1];
    const float* Whh  = (const float*)d_in[2];
    const float* bih  = (const float*)d_in[3];
    const float* bhh  = (const float*)d_in[4];
    const float* Wcls = (const float*)d_in[5];
    const float* bcls = (const float*)d_in[6];

    float*    meanf  = (float*)d_ws;                          // 64*128 f32 = 32 KB
    unsigned* ticket = (unsigned*)((char*)d_ws + 64 * HID * 4);

    // zero mean accumulator + ticket (captured into the graph, runs every replay)
    hipMemsetAsync(d_ws, 0, 64 * HID * 4 + 64, stream);

    lstm_fused<<<NSEQ / 8, 512, 0, stream>>>(x, Wih, Whh, bih, bhh,
                                             Wcls, bcls, meanf, ticket,
                                             (float*)d_out);
}

// Round 7
// 199.962 us; speedup vs baseline: 1.1846x; 1.1846x over previous
//
#include <hip/hip_runtime.h>
#include <hip/hip_bf16.h>

// Problem constants: G=64, C=32, L=128, D=64, H=128, NCLS=10
#define NSEQ 2048   // G*C
#define LSEQ 128
#define DIN  64
#define HID  128
#define NCLS 10
#define XPAD 72     // padded x row (shorts)
#define CHK  16     // timesteps staged per chunk

typedef __attribute__((ext_vector_type(8))) short bfrag8;   // 8 bf16 (MFMA A/B frag)
typedef __attribute__((ext_vector_type(4))) float facc4;    // MFMA C/D frag

__device__ __forceinline__ short f2bf(float f) {
    union { __hip_bfloat16 b; short s; } u;
    u.b = __float2bfloat16(f);   // RNE
    return u.s;
}

__device__ __forceinline__ bfrag8 load_bf16_frag(const float* __restrict__ p) {
    bfrag8 r;
#pragma unroll
    for (int j = 0; j < 8; ++j) r[j] = f2bf(p[j]);
    return r;
}

__device__ __forceinline__ float fast_sigmoid(float x) {
    float e = __builtin_amdgcn_exp2f(-1.4426950408889634f * x);
    return __builtin_amdgcn_rcpf(1.0f + e);
}
__device__ __forceinline__ float fast_tanh(float x) {
    float e = __builtin_amdgcn_exp2f(2.8853900817779268f * x);
    return 1.0f - 2.0f * __builtin_amdgcn_rcpf(1.0f + e);
}

// v_permlane32_swap_b32 d, s : exchanges d.lanes[32:63] with s.lanes[0:31]
// (R6 evidence: the opposite orientation delivered h=0 padding rows to all
// lanes -> bounded 0.477 error; this orientation is the consistent one).
// With d = r_low (r0/r1), s = r_high (r2/r3):
//   d_new.lo = own r_low  (rows 0,1 / 4,5 — valid)
//   d_new.hi = r_high of lanes 0..31 (rows 2,3 / 6,7 — valid)
// -> returned d holds each lane's 2 valid cell-units per the seq map
//    qd0:{0,1} qd1:{4,5} qd2:{2,3} qd3:{6,7}. One VALU op, no LDS traffic.
__device__ __forceinline__ float lane_redistribute(float r_low, float r_high) {
    float d = r_low, s = r_high;
    asm("v_permlane32_swap_b32 %0, %1" : "+v"(d), "+v"(s));
    return d;
}

// One block = 8 sequences (M=16 padded), 8 waves; wave w owns gate columns
// {g*128 + w*16} -> lane's 4 C-frags are i,f,g,o of its 16 hidden units.
// permlane32_swap redistributes the 8 valid C-rows so all 64 lanes run 2
// valid cell-units. x(t+1) MFMAs + reads issue during step t's cell phase.
__global__ __launch_bounds__(512) void lstm_fused(
    const float* __restrict__ x,      // [2048][128][64] f32
    const float* __restrict__ Wih,    // [512][64] f32
    const float* __restrict__ Whh,    // [512][128] f32
    const float* __restrict__ bih,    // [512] f32
    const float* __restrict__ bhh,    // [512] f32
    float* __restrict__ rep)          // [2048][128] f32 (d_ws)
{
    __shared__ __align__(16) __hip_bfloat16 hbuf[2][16][136];          // 8704 B
    __shared__ __align__(16) __hip_bfloat16 xs[2][CHK][8][XPAD];       // 36864 B

    const int tid  = threadIdx.x;
    const int w    = tid >> 6;
    const int lane = tid & 63;
    const int ln   = lane & 15;
    const int qd   = lane >> 4;
    const int s0   = blockIdx.x * 8;
    const int khid = w * 16 + ln;
    // this lane's two assigned sequences after the half-exchange
    const int sq0  = (qd & 1) * 4 + (qd >> 1) * 2;   // {0,4,2,6}
    const int sq1  = sq0 + 1;                        // {1,5,3,7}

    // ---- weight B-fragments: f32 -> bf16 registers (reused all 128 steps) ----
    bfrag8 whh[4][4];
    bfrag8 wih[4][2];
    float  biasv[4];
#pragma unroll
    for (int g = 0; g < 4; ++g) {
        const int col = g * HID + khid;
        biasv[g] = bih[col] + bhh[col];
#pragma unroll
        for (int k0 = 0; k0 < 4; ++k0)
            whh[g][k0] = load_bf16_frag(Whh + col * HID + k0 * 32 + qd * 8);
#pragma unroll
        for (int k0 = 0; k0 < 2; ++k0)
            wih[g][k0] = load_bf16_frag(Wih + col * DIN + k0 * 32 + qd * 8);
    }

    // zero both h buffers (rows 8..15 stay zero -> padded M rows read 0)
    {
        unsigned int* p = (unsigned int*)&hbuf[0][0][0];
        for (int i = tid; i < 2 * 16 * 136 / 2; i += 512) p[i] = 0u;
    }

    // x staging: wave w stages sequence s0+w; lane covers 16 consecutive f32.
    const float* xsrc = x + (size_t)(s0 + w) * (LSEQ * DIN) + lane * 16;
    const int stt = lane >> 2;
    const int sdd = (lane & 3) * 16;

    {   // stage chunk 0
        float4 a0 = ((const float4*)xsrc)[0];
        float4 a1 = ((const float4*)xsrc)[1];
        float4 a2 = ((const float4*)xsrc)[2];
        float4 a3 = ((const float4*)xsrc)[3];
        bfrag8 o0, o1;
#pragma unroll
        for (int j = 0; j < 4; ++j) { o0[j] = f2bf(((float*)&a0)[j]); o0[4+j] = f2bf(((float*)&a1)[j]); }
#pragma unroll
        for (int j = 0; j < 4; ++j) { o1[j] = f2bf(((float*)&a2)[j]); o1[4+j] = f2bf(((float*)&a3)[j]); }
        *(bfrag8*)&xs[0][stt][w][sdd]     = o0;
        *(bfrag8*)&xs[0][stt][w][sdd + 8] = o1;
    }

    float cst[2]  = {0.f, 0.f};
    float hsum[2] = {0.f, 0.f};

    __syncthreads();

    // prologue: acc for t=0 = bias + x(0) @ Wih^T
    facc4 accA[4], accB[4];
    {
        bfrag8 x0 = *(const bfrag8*)(&xs[0][0][ln & 7][qd * 8]);
        bfrag8 x1 = *(const bfrag8*)(&xs[0][0][ln & 7][32 + qd * 8]);
#pragma unroll
        for (int g = 0; g < 4; ++g) {
            accA[g] = (facc4){biasv[g], biasv[g], biasv[g], biasv[g]};
            accA[g] = __builtin_amdgcn_mfma_f32_16x16x32_bf16(x0, wih[g][0], accA[g], 0, 0, 0);
            accA[g] = __builtin_amdgcn_mfma_f32_16x16x32_bf16(x1, wih[g][1], accA[g], 0, 0, 0);
        }
    }

    int cur = 0;

#define STEP(ACCIN, ACCOUT, CT)                                                          \
    {                                                                                    \
        const int ct = (CT);                                                             \
        /* h A-frags (post-barrier critical path) */                                     \
        bfrag8 hf[4];                                                                    \
        _Pragma("unroll")                                                                \
        for (int k0 = 0; k0 < 4; ++k0)                                                   \
            hf[k0] = *(const bfrag8*)(&hbuf[cur][ln][k0 * 32 + qd * 8]);                 \
        /* x A-frags for t+1 (stable chunk buffer; ct==15 -> next chunk's buffer) */     \
        const int nbuf = (ct < CHK - 1) ? buf : (buf ^ 1);                               \
        const int nct  = (ct + 1) & (CHK - 1);                                           \
        bfrag8 xf0 = *(const bfrag8*)(&xs[nbuf][nct][ln & 7][qd * 8]);                   \
        bfrag8 xf1 = *(const bfrag8*)(&xs[nbuf][nct][ln & 7][32 + qd * 8]);              \
        /* h-part MFMAs into carried acc (which already holds bias + x(t)) */            \
        _Pragma("unroll")                                                                \
        for (int g = 0; g < 4; ++g)                                                      \
            _Pragma("unroll")                                                            \
            for (int k0 = 0; k0 < 4; ++k0)                                               \
                ACCIN[g] = __builtin_amdgcn_mfma_f32_16x16x32_bf16(hf[k0], whh[g][k0], ACCIN[g], 0, 0, 0); \
        /* redistribute valid rows: 1 VALU op per pair, no LDS, no cndmask */            \
        float u0[4], u1[4];                                                              \
        _Pragma("unroll")                                                                \
        for (int g = 0; g < 4; ++g) {                                                    \
            u0[g] = lane_redistribute(ACCIN[g][0], ACCIN[g][2]);                         \
            u1[g] = lane_redistribute(ACCIN[g][1], ACCIN[g][3]);                         \
        }                                                                                \
        /* next step's x-part: fills MFMA pipe during cell phase */                      \
        _Pragma("unroll")                                                                \
        for (int g = 0; g < 4; ++g) {                                                    \
            ACCOUT[g] = (facc4){biasv[g], biasv[g], biasv[g], biasv[g]};                 \
            ACCOUT[g] = __builtin_amdgcn_mfma_f32_16x16x32_bf16(xf0, wih[g][0], ACCOUT[g], 0, 0, 0); \
            ACCOUT[g] = __builtin_amdgcn_mfma_f32_16x16x32_bf16(xf1, wih[g][1], ACCOUT[g], 0, 0, 0); \
        }                                                                                \
        if (ct == 0 && more) {      /* issue next chunk's global loads */                \
            const float* p = xsrc + (chunk + 1) * (CHK * DIN);                           \
            l0 = ((const float4*)p)[0];                                                  \
            l1 = ((const float4*)p)[1];                                                  \
            l2 = ((const float4*)p)[2];                                                  \
            l3 = ((const float4*)p)[3];                                                  \
        }                                                                                \
        if (ct == 12 && more) {     /* convert + write next chunk to LDS */              \
            bfrag8 o0, o1;                                                               \
            _Pragma("unroll")                                                            \
            for (int j = 0; j < 4; ++j) { o0[j] = f2bf(((float*)&l0)[j]); o0[4+j] = f2bf(((float*)&l1)[j]); } \
            _Pragma("unroll")                                                            \
            for (int j = 0; j < 4; ++j) { o1[j] = f2bf(((float*)&l2)[j]); o1[4+j] = f2bf(((float*)&l3)[j]); } \
            *(bfrag8*)&xs[buf ^ 1][stt][w][sdd]     = o0;                                \
            *(bfrag8*)&xs[buf ^ 1][stt][w][sdd + 8] = o1;                                \
        }                                                                                \
        /* LSTM cell on this lane's 2 assigned (seq, hid) units */                       \
        short hb[2];                                                                     \
        _Pragma("unroll")                                                                \
        for (int j = 0; j < 2; ++j) {                                                    \
            float iv = fast_sigmoid(j ? u1[0] : u0[0]);                                  \
            float fv = fast_sigmoid(j ? u1[1] : u0[1]);                                  \
            float gv = fast_tanh(j ? u1[2] : u0[2]);                                     \
            float ov = fast_sigmoid(j ? u1[3] : u0[3]);                                  \
            float c  = fv * cst[j] + iv * gv;                                            \
            cst[j]   = c;                                                                \
            float hv = ov * fast_tanh(c);                                                \
            hsum[j] += hv;                                                               \
            hb[j]    = f2bf(hv);                                                         \
        }                                                                                \
        ((short*)&hbuf[cur ^ 1][sq0][0])[khid] = hb[0];                                  \
        ((short*)&hbuf[cur ^ 1][sq1][0])[khid] = hb[1];                                  \
        __syncthreads();                                                                 \
        cur ^= 1;                                                                        \
    }

    for (int chunk = 0; chunk < LSEQ / CHK; ++chunk) {
        const int buf = chunk & 1;
        const bool more = chunk < (LSEQ / CHK - 1);
        float4 l0, l1, l2, l3;
#pragma unroll 1
        for (int ct2 = 0; ct2 < CHK / 2; ++ct2) {
            STEP(accA, accB, 2 * ct2);
            STEP(accB, accA, 2 * ct2 + 1);
        }
    }
#undef STEP

    // rep[b][k] = sum_t h_t[b][k] — every lane writes its 2 assigned seqs
    rep[(size_t)(s0 + sq0) * HID + khid] = hsum[0];
    rep[(size_t)(s0 + sq1) * HID + khid] = hsum[1];
}

// Epilogue: graph mean over C=32, classifier [10,128], log-softmax -> f32 out[64][10]
__global__ __launch_bounds__(128) void cls_kernel(
    const float* __restrict__ rep,    // [2048][128]
    const float* __restrict__ Wcls,   // [10][128]
    const float* __restrict__ bcls,   // [10]
    float* __restrict__ out)          // [64][10]
{
    __shared__ float m_s[HID];
    __shared__ float logits_s[NCLS];
    const int g = blockIdx.x;
    const int h = threadIdx.x;

    float s = 0.f;
#pragma unroll 4
    for (int c = 0; c < 32; ++c)
        s += rep[((size_t)g * 32 + c) * HID + h];
    m_s[h] = s * (1.0f / 32.0f);
    __syncthreads();

    if (h < NCLS) {
        float acc = bcls[h];
        for (int k = 0; k < HID; ++k)
            acc += m_s[k] * Wcls[h * HID + k];
        logits_s[h] = acc;
    }
    __syncthreads();

    if (h < NCLS) {
        float mx = logits_s[0];
#pragma unroll
        for (int j = 1; j < NCLS; ++j) mx = fmaxf(mx, logits_s[j]);
        float se = 0.f;
#pragma unroll
        for (int j = 0; j < NCLS; ++j)
            se += __builtin_amdgcn_exp2f((logits_s[j] - mx) * 1.4426950408889634f);
        float lse = mx + 0.6931471805599453f * __builtin_amdgcn_logf(se);
        out[g * NCLS + h] = logits_s[h] - lse;
    }
}

extern "C" void kernel_launch(void* const* d_in, const int* in_sizes, int n_in,
                              void* d_out, int out_size, void* d_ws, size_t ws_size,
                              hipStream_t stream) {
    const float* x    = (const float*)d_in[0];
    const float* Wih  = (const float*)d_in[1];
    const float* Whh  = (const float*)d_in[2];
    const float* bih  = (const float*)d_in[3];
    const float* bhh  = (const float*)d_in[4];
    const float* Wcls = (const float*)d_in[5];
    const float* bcls = (const float*)d_in[6];

    float* rep = (float*)d_ws;   // 2048*128 fp32 = 1 MB scratch

    lstm_fused<<<NSEQ / 8, 512, 0, stream>>>(x, Wih, Whh, bih, bhh, rep);
    cls_kernel<<<64, 128, 0, stream>>>(rep, Wcls, bcls, (float*)d_out);
}

// Round 9
// 198.944 us; speedup vs baseline: 1.1907x; 1.0051x over previous
//
#include <hip/hip_runtime.h>
#include <hip/hip_bf16.h>

// Problem constants: G=64, C=32, L=128, D=64, H=128, NCLS=10
#define NSEQ 2048   // G*C
#define LSEQ 128
#define DIN  64
#define HID  128
#define NCLS 10
#define XPAD 72     // padded x row (shorts)
#define CHK  16     // timesteps staged per chunk

typedef __attribute__((ext_vector_type(8))) short bfrag8;   // 8 bf16 (MFMA A/B frag)
typedef __attribute__((ext_vector_type(4))) float facc4;    // MFMA C/D frag

__device__ __forceinline__ short f2bf(float f) {
    union { __hip_bfloat16 b; short s; } u;
    u.b = __float2bfloat16(f);   // RNE
    return u.s;
}

__device__ __forceinline__ bfrag8 load_bf16_frag(const float* __restrict__ p) {
    bfrag8 r;
#pragma unroll
    for (int j = 0; j < 8; ++j) r[j] = f2bf(p[j]);
    return r;
}

__device__ __forceinline__ float fast_sigmoid(float x) {
    float e = __builtin_amdgcn_exp2f(-1.4426950408889634f * x);
    return __builtin_amdgcn_rcpf(1.0f + e);
}
__device__ __forceinline__ float fast_tanh(float x) {
    float e = __builtin_amdgcn_exp2f(2.8853900817779268f * x);
    return 1.0f - 2.0f * __builtin_amdgcn_rcpf(1.0f + e);
}

// v_permlane32_swap_b32 d, s — HW-verified (R7 pass) d-output semantics:
//   d_new.lo = d_old.lo ; d_new.hi[i+32] = s_old[i]  (lo-lane s values -> hi d lanes)
// The s-output is NOT relied upon (R8 evidence: consuming it produced wrong
// results; only the d-output is verified). d = r_low, s = r_high, return d:
// lo lanes keep rows 0/4, hi lanes receive rows 2/6 from the low half ->
// seq map qd0:{0,1} qd1:{4,5} qd2:{2,3} qd3:{6,7}.
__device__ __forceinline__ float lane_redistribute(float r_low, float r_high) {
    float d = r_low, s = r_high;
    asm("v_permlane32_swap_b32 %0, %1" : "+v"(d), "+v"(s));
    return d;
}

// One block = 8 sequences (M=16 padded), 8 waves; wave w owns gate columns
// {g*128 + w*16} -> lane's 4 C-frags are i,f,g,o of its 16 hidden units.
// permlane32_swap redistributes the 8 valid C-rows so all 64 lanes run 2
// valid cell-units. x(t+1) MFMAs + reads issue during step t's cell phase.
// Bias rides as a persistent MFMA C-operand (biasf) — no per-step acc init.
__global__ __launch_bounds__(512) void lstm_fused(
    const float* __restrict__ x,      // [2048][128][64] f32
    const float* __restrict__ Wih,    // [512][64] f32
    const float* __restrict__ Whh,    // [512][128] f32
    const float* __restrict__ bih,    // [512] f32
    const float* __restrict__ bhh,    // [512] f32
    float* __restrict__ rep)          // [2048][128] f32 (d_ws)
{
    __shared__ __align__(16) __hip_bfloat16 hbuf[2][16][136];          // 8704 B
    __shared__ __align__(16) __hip_bfloat16 xs[2][CHK][8][XPAD];       // 36864 B

    const int tid  = threadIdx.x;
    const int w    = tid >> 6;
    const int lane = tid & 63;
    const int ln   = lane & 15;
    const int qd   = lane >> 4;
    const int s0   = blockIdx.x * 8;
    const int khid = w * 16 + ln;
    // this lane's two assigned sequences after the half-exchange
    const int sq0  = (qd & 1) * 4 + (qd >> 1) * 2;   // {0,4,2,6}
    const int sq1  = sq0 + 1;                        // {1,5,3,7}

    // ---- weight B-fragments: f32 -> bf16 registers (reused all 128 steps) ----
    bfrag8 whh[4][4];
    bfrag8 wih[4][2];
    facc4  biasf[4];    // bias as persistent MFMA C-input
#pragma unroll
    for (int g = 0; g < 4; ++g) {
        const int col = g * HID + khid;
        const float b = bih[col] + bhh[col];
        biasf[g] = (facc4){b, b, b, b};
#pragma unroll
        for (int k0 = 0; k0 < 4; ++k0)
            whh[g][k0] = load_bf16_frag(Whh + col * HID + k0 * 32 + qd * 8);
#pragma unroll
        for (int k0 = 0; k0 < 2; ++k0)
            wih[g][k0] = load_bf16_frag(Wih + col * DIN + k0 * 32 + qd * 8);
    }

    // zero both h buffers (rows 8..15 stay zero -> padded M rows read 0)
    {
        unsigned int* p = (unsigned int*)&hbuf[0][0][0];
        for (int i = tid; i < 2 * 16 * 136 / 2; i += 512) p[i] = 0u;
    }

    // x staging: wave w stages sequence s0+w; lane covers 16 consecutive f32.
    const float* xsrc = x + (size_t)(s0 + w) * (LSEQ * DIN) + lane * 16;
    const int stt = lane >> 2;
    const int sdd = (lane & 3) * 16;

    {   // stage chunk 0
        float4 a0 = ((const float4*)xsrc)[0];
        float4 a1 = ((const float4*)xsrc)[1];
        float4 a2 = ((const float4*)xsrc)[2];
        float4 a3 = ((const float4*)xsrc)[3];
        bfrag8 o0, o1;
#pragma unroll
        for (int j = 0; j < 4; ++j) { o0[j] = f2bf(((float*)&a0)[j]); o0[4+j] = f2bf(((float*)&a1)[j]); }
#pragma unroll
        for (int j = 0; j < 4; ++j) { o1[j] = f2bf(((float*)&a2)[j]); o1[4+j] = f2bf(((float*)&a3)[j]); }
        *(bfrag8*)&xs[0][stt][w][sdd]     = o0;
        *(bfrag8*)&xs[0][stt][w][sdd + 8] = o1;
    }

    float cst[2]  = {0.f, 0.f};
    float hsum[2] = {0.f, 0.f};

    __syncthreads();

    // prologue: acc for t=0 = bias + x(0) @ Wih^T
    facc4 accA[4], accB[4];
    {
        bfrag8 x0 = *(const bfrag8*)(&xs[0][0][ln & 7][qd * 8]);
        bfrag8 x1 = *(const bfrag8*)(&xs[0][0][ln & 7][32 + qd * 8]);
#pragma unroll
        for (int g = 0; g < 4; ++g) {
            accA[g] = __builtin_amdgcn_mfma_f32_16x16x32_bf16(x0, wih[g][0], biasf[g], 0, 0, 0);
            accA[g] = __builtin_amdgcn_mfma_f32_16x16x32_bf16(x1, wih[g][1], accA[g], 0, 0, 0);
        }
    }

    int cur = 0;

#define STEP(ACCIN, ACCOUT, CT)                                                          \
    {                                                                                    \
        const int ct = (CT);                                                             \
        /* h A-frags (post-barrier critical path) */                                     \
        bfrag8 hf[4];                                                                    \
        _Pragma("unroll")                                                                \
        for (int k0 = 0; k0 < 4; ++k0)                                                   \
            hf[k0] = *(const bfrag8*)(&hbuf[cur][ln][k0 * 32 + qd * 8]);                 \
        /* x A-frags for t+1 (stable chunk buffer; ct==15 -> next chunk's buffer) */     \
        const int nbuf = (ct < CHK - 1) ? buf : (buf ^ 1);                               \
        const int nct  = (ct + 1) & (CHK - 1);                                           \
        bfrag8 xf0 = *(const bfrag8*)(&xs[nbuf][nct][ln & 7][qd * 8]);                   \
        bfrag8 xf1 = *(const bfrag8*)(&xs[nbuf][nct][ln & 7][32 + qd * 8]);              \
        /* h-part MFMAs into carried acc (which already holds bias + x(t)) */            \
        _Pragma("unroll")                                                                \
        for (int g = 0; g < 4; ++g)                                                      \
            _Pragma("unroll")                                                            \
            for (int k0 = 0; k0 < 4; ++k0)                                               \
                ACCIN[g] = __builtin_amdgcn_mfma_f32_16x16x32_bf16(hf[k0], whh[g][k0], ACCIN[g], 0, 0, 0); \
        /* redistribute valid rows: 1 VALU op per pair (d-output only) */                \
        float u0[4], u1[4];                                                              \
        _Pragma("unroll")                                                                \
        for (int g = 0; g < 4; ++g) {                                                    \
            u0[g] = lane_redistribute(ACCIN[g][0], ACCIN[g][2]);                         \
            u1[g] = lane_redistribute(ACCIN[g][1], ACCIN[g][3]);                         \
        }                                                                                \
        /* next step's x-part: fills MFMA pipe during cell phase (C = biasf) */          \
        _Pragma("unroll")                                                                \
        for (int g = 0; g < 4; ++g) {                                                    \
            ACCOUT[g] = __builtin_amdgcn_mfma_f32_16x16x32_bf16(xf0, wih[g][0], biasf[g], 0, 0, 0); \
            ACCOUT[g] = __builtin_amdgcn_mfma_f32_16x16x32_bf16(xf1, wih[g][1], ACCOUT[g], 0, 0, 0); \
        }                                                                                \
        if (ct == 0 && more) {      /* issue next chunk's global loads */                \
            const float* p = xsrc + (chunk + 1) * (CHK * DIN);                           \
            l0 = ((const float4*)p)[0];                                                  \
            l1 = ((const float4*)p)[1];                                                  \
            l2 = ((const float4*)p)[2];                                                  \
            l3 = ((const float4*)p)[3];                                                  \
        }                                                                                \
        if (ct == 12 && more) {     /* convert + write next chunk to LDS */              \
            bfrag8 o0, o1;                                                               \
            _Pragma("unroll")                                                            \
            for (int j = 0; j < 4; ++j) { o0[j] = f2bf(((float*)&l0)[j]); o0[4+j] = f2bf(((float*)&l1)[j]); } \
            _Pragma("unroll")                                                            \
            for (int j = 0; j < 4; ++j) { o1[j] = f2bf(((float*)&l2)[j]); o1[4+j] = f2bf(((float*)&l3)[j]); } \
            *(bfrag8*)&xs[buf ^ 1][stt][w][sdd]     = o0;                                \
            *(bfrag8*)&xs[buf ^ 1][stt][w][sdd + 8] = o1;                                \
        }                                                                                \
        /* LSTM cell on this lane's 2 assigned (seq, hid) units */                       \
        short hb[2];                                                                     \
        _Pragma("unroll")                                                                \
        for (int j = 0; j < 2; ++j) {                                                    \
            float iv = fast_sigmoid(j ? u1[0] : u0[0]);                                  \
            float fv = fast_sigmoid(j ? u1[1] : u0[1]);                                  \
            float gv = fast_tanh(j ? u1[2] : u0[2]);                                     \
            float ov = fast_sigmoid(j ? u1[3] : u0[3]);                                  \
            float c  = fv * cst[j] + iv * gv;                                            \
            cst[j]   = c;                                                                \
            float hv = ov * fast_tanh(c);                                                \
            hsum[j] += hv;                                                               \
            hb[j]    = f2bf(hv);                                                         \
        }                                                                                \
        ((short*)&hbuf[cur ^ 1][sq0][0])[khid] = hb[0];                                  \
        ((short*)&hbuf[cur ^ 1][sq1][0])[khid] = hb[1];                                  \
        __syncthreads();                                                                 \
        cur ^= 1;                                                                        \
    }

    for (int chunk = 0; chunk < LSEQ / CHK; ++chunk) {
        const int buf = chunk & 1;
        const bool more = chunk < (LSEQ / CHK - 1);
        float4 l0, l1, l2, l3;
#pragma unroll 1
        for (int ct2 = 0; ct2 < CHK / 2; ++ct2) {
            STEP(accA, accB, 2 * ct2);
            STEP(accB, accA, 2 * ct2 + 1);
        }
    }
#undef STEP

    // rep[b][k] = sum_t h_t[b][k] — every lane writes its 2 assigned seqs
    rep[(size_t)(s0 + sq0) * HID + khid] = hsum[0];
    rep[(size_t)(s0 + sq1) * HID + khid] = hsum[1];
}

// Epilogue: graph mean over C=32, classifier [10,128], log-softmax -> f32 out[64][10]
__global__ __launch_bounds__(128) void cls_kernel(
    const float* __restrict__ rep,    // [2048][128]
    const float* __restrict__ Wcls,   // [10][128]
    const float* __restrict__ bcls,   // [10]
    float* __restrict__ out)          // [64][10]
{
    __shared__ float m_s[HID];
    __shared__ float logits_s[NCLS];
    const int g = blockIdx.x;
    const int h = threadIdx.x;

    float s = 0.f;
#pragma unroll 4
    for (int c = 0; c < 32; ++c)
        s += rep[((size_t)g * 32 + c) * HID + h];
    m_s[h] = s * (1.0f / 32.0f);
    __syncthreads();

    if (h < NCLS) {
        float acc = bcls[h];
        for (int k = 0; k < HID; ++k)
            acc += m_s[k] * Wcls[h * HID + k];
        logits_s[h] = acc;
    }
    __syncthreads();

    if (h < NCLS) {
        float mx = logits_s[0];
#pragma unroll
        for (int j = 1; j < NCLS; ++j) mx = fmaxf(mx, logits_s[j]);
        float se = 0.f;
#pragma unroll
        for (int j = 0; j < NCLS; ++j)
            se += __builtin_amdgcn_exp2f((logits_s[j] - mx) * 1.4426950408889634f);
        float lse = mx + 0.6931471805599453f * __builtin_amdgcn_logf(se);
        out[g * NCLS + h] = logits_s[h] - lse;
    }
}

extern "C" void kernel_launch(void* const* d_in, const int* in_sizes, int n_in,
                              void* d_out, int out_size, void* d_ws, size_t ws_size,
                              hipStream_t stream) {
    const float* x    = (const float*)d_in[0];
    const float* Wih  = (const float*)d_in[1];
    const float* Whh  = (const float*)d_in[2];
    const float* bih  = (const float*)d_in[3];
    const float* bhh  = (const float*)d_in[4];
    const float* Wcls = (const float*)d_in[5];
    const float* bcls = (const float*)d_in[6];

    float* rep = (float*)d_ws;   // 2048*128 fp32 = 1 MB scratch

    lstm_fused<<<NSEQ / 8, 512, 0, stream>>>(x, Wih, Whh, bih, bhh, rep);
    cls_kernel<<<64, 128, 0, stream>>>(rep, Wcls, bcls, (float*)d_out);
}